// Round 2
// baseline (113.562 us; speedup 1.0000x reference)
//
#include <hip/hip_runtime.h>

#define N_DIM 4096

typedef float f4  __attribute__((ext_vector_type(4)));
typedef short s8v __attribute__((ext_vector_type(8)));

#if defined(__has_builtin)
#if __has_builtin(__builtin_amdgcn_cvt_pk_bf16_f32)
#define HAVE_CVT_PK 1
#endif
#endif

static __device__ __forceinline__ unsigned int f2bf_pair(float lo, float hi) {
#ifdef HAVE_CVT_PK
    typedef __bf16 bf2 __attribute__((ext_vector_type(2)));
    bf2 p = __builtin_amdgcn_cvt_pk_bf16_f32(lo, hi);
    return __builtin_bit_cast(unsigned int, p);
#else
    unsigned int ul = __builtin_bit_cast(unsigned int, lo);
    unsigned int uh = __builtin_bit_cast(unsigned int, hi);
    ul = ul + 0x7fffu + ((ul >> 16) & 1u);
    uh = uh + 0x7fffu + ((uh >> 16) & 1u);
    return (uh & 0xffff0000u) | (ul >> 16);
#endif
}

static __device__ __forceinline__ s8v cvt8(f4 a, f4 b) {
    unsigned int u4[4] = { f2bf_pair(a[0], a[1]), f2bf_pair(a[2], a[3]),
                           f2bf_pair(b[0], b[1]), f2bf_pair(b[2], b[3]) };
    return __builtin_bit_cast(s8v, u4);
}

#define MFMA(a, b, c) __builtin_amdgcn_mfma_f32_16x16x32_bf16((a), (b), (c), 0, 0, 0)

// Fused gemm+epilogue: grid=256 blocks (one 16-row i-tile each), 512 threads
// (8 waves: kh = w&3 k-tile, nh = w>>2 n-half). Full n=4096 contraction per
// block in 32 double-buffered 128-col chunks (XOR-swizzled LDS, raw
// lgkm-only barrier, global prefetch distance 2, named regs per rule #20).
// Epilogue in-block: cross-wave acc combine via LDS, exact-fp32 num,
// den = gemm_row_sum - num, one float per block to ws. No part buffer.
__global__ __launch_bounds__(512) void fused_kernel(
    const float* __restrict__ zs, const float* __restrict__ X,
    const float* __restrict__ varp, float* __restrict__ bsum) {
    __shared__ s8v zsP[2][1024];   // 64 k x 128 n bf16, dbuf (32 KB)
    __shared__ s8v xP [2][256];    // 16 i x 128 n bf16, dbuf (8 KB)
    __shared__ f4  accx[256];      // nh=1 partial accs (4 KB)
    __shared__ float wred[8];

    const int tid  = threadIdx.x;
    const int lane = tid & 63;
    const int w    = tid >> 6;
    const int kh   = w & 3;
    const int nh   = w >> 2;
    const int i0   = blockIdx.x * 16;

    // ---- staging geometry (write side) ----
    const int zr  = tid >> 3;                       // zs row (k), 0..63
    const int zc  = tid & 7;                        // granule col base, +8 for 2nd
    const int zi0 = zr * 16 + (zc ^ (zr & 7));      // XOR swizzle (R8-verified)
    const int zi1 = zi0 + 8;
    const float* gz = zs + (size_t)zr * N_DIM + zc * 8;

    const int xr  = (tid & 255) >> 4;               // X row (i), 0..15 (tid<256)
    const int xc  = tid & 15;
    const int xi  = xr * 16 + (xc ^ (xr & 7));
    const float* gx = X + (size_t)(i0 + xr) * N_DIM + xc * 8;

    // ---- read-side swizzled indices (row&7 == lane&7 for both A and B) ----
    const int arow = kh * 16 + (lane & 15);
    const int brow = lane & 15;
    const int cb0  = nh * 8 + (lane >> 4);          // unswizzled granule col, step 0
    const int ai0  = arow * 16 + ((cb0    ) ^ (lane & 7));
    const int ai1  = arow * 16 + ((cb0 + 4) ^ (lane & 7));
    const int bi0  = brow * 16 + ((cb0    ) ^ (lane & 7));
    const int bi1  = brow * 16 + ((cb0 + 4) ^ (lane & 7));

    // ---- prologue: prefetch chunk 0 into A-regs, chunk 1 into B-regs ----
    f4 rzA0, rzA1, rzA2, rzA3, rzB0, rzB1, rzB2, rzB3;
    f4 rxA0 = {}, rxA1 = {}, rxB0 = {}, rxB1 = {};
    rzA0 = *(const f4*)(gz);       rzA1 = *(const f4*)(gz + 4);
    rzA2 = *(const f4*)(gz + 64);  rzA3 = *(const f4*)(gz + 68);
    rzB0 = *(const f4*)(gz + 128); rzB1 = *(const f4*)(gz + 132);
    rzB2 = *(const f4*)(gz + 192); rzB3 = *(const f4*)(gz + 196);
    if (tid < 256) {
        rxA0 = *(const f4*)(gx);       rxA1 = *(const f4*)(gx + 4);
        rxB0 = *(const f4*)(gx + 128); rxB1 = *(const f4*)(gx + 132);
    }

    f4 acc = {};

#define STEP(L, BI, T)                                                        \
    {                                                                         \
        s8v pz0 = cvt8(rz##L##0, rz##L##1);                                   \
        s8v pz1 = cvt8(rz##L##2, rz##L##3);                                   \
        s8v px0 = {};                                                         \
        if (tid < 256) px0 = cvt8(rx##L##0, rx##L##1);                        \
        if ((T) < 30) {   /* issue chunk T+2 into the slot just consumed */   \
            const float* z = gz + ((T) + 2) * 128;                            \
            rz##L##0 = *(const f4*)(z);      rz##L##1 = *(const f4*)(z + 4);  \
            rz##L##2 = *(const f4*)(z + 64); rz##L##3 = *(const f4*)(z + 68); \
            if (tid < 256) {                                                  \
                const float* x = gx + ((T) + 2) * 128;                        \
                rx##L##0 = *(const f4*)(x);  rx##L##1 = *(const f4*)(x + 4);  \
            }                                                                 \
        }                                                                     \
        zsP[BI][zi0] = pz0; zsP[BI][zi1] = pz1;                               \
        if (tid < 256) xP[BI][xi] = px0;                                      \
        asm volatile("s_waitcnt lgkmcnt(0)\n\ts_barrier" ::: "memory");       \
        s8v a0 = zsP[BI][ai0], b0 = xP[BI][bi0];                              \
        s8v a1 = zsP[BI][ai1], b1 = xP[BI][bi1];                              \
        acc = MFMA(a0, b0, acc);                                              \
        acc = MFMA(a1, b1, acc);                                              \
    }

    for (int m = 0; m < 16; ++m) {
        STEP(A, 0, 2 * m)
        STEP(B, 1, 2 * m + 1)
    }
#undef STEP

    // ---- cross-wave combine (nh=1 -> nh=0) ----
    if (nh == 1) accx[kh * 64 + lane] = acc;
    __syncthreads();

    float vsum = 0.f;
    if (nh == 0) {
        f4 o = accx[kh * 64 + lane];
        // C/D layout: col = lane&15 (i), row = (lane>>4)*4 + r (k)
        const int   i   = i0 + (lane & 15);
        const float dg  = X[(size_t)i * (N_DIM + 1)];
        const float var = varp[0];
        #pragma unroll
        for (int r = 0; r < 4; ++r) {
            const int   k   = kh * 16 + (lane >> 4) * 4 + r;
            const float num = zs[(size_t)k * N_DIM + i] * dg;   // exact fp32
            const float den = (acc[r] + o[r]) - num;
            vsum += num / (var + den);
        }
    }
    #pragma unroll
    for (int off = 32; off >= 1; off >>= 1) vsum += __shfl_down(vsum, off);
    if (lane == 0) wred[w] = vsum;
    __syncthreads();
    if (tid == 0) bsum[blockIdx.x] = wred[0] + wred[1] + wred[2] + wred[3];
}

// Deterministic final reduce: 256 block partials -> scalar. No atomics, no
// out-zeroing dependency.
__global__ __launch_bounds__(256) void reduce_kernel(
    const float* __restrict__ bsum, float* __restrict__ out) {
    const int tid = threadIdx.x;
    float v = bsum[tid];
    #pragma unroll
    for (int off = 32; off >= 1; off >>= 1) v += __shfl_down(v, off);
    __shared__ float s4[4];
    if ((tid & 63) == 0) s4[tid >> 6] = v;
    __syncthreads();
    if (tid == 0) *out = -(s4[0] + s4[1] + s4[2] + s4[3]) * (1.0f / 64.0f);
}

extern "C" void kernel_launch(void* const* d_in, const int* in_sizes, int n_in,
                              void* d_out, int out_size, void* d_ws, size_t ws_size,
                              hipStream_t stream) {
    const float* zs   = (const float*)d_in[0];
    const float* X    = (const float*)d_in[1];
    const float* varp = (const float*)d_in[2];
    float* out  = (float*)d_out;
    float* bsum = (float*)d_ws;      // 256 floats

    hipLaunchKernelGGL(fused_kernel, dim3(256), dim3(512), 0, stream,
                       zs, X, varp, bsum);
    hipLaunchKernelGGL(reduce_kernel, dim3(1), dim3(256), 0, stream,
                       bsum, out);
}

// Round 3
// 112.252 us; speedup vs baseline: 1.0117x; 1.0117x over previous
//
#include <hip/hip_runtime.h>

#define N_DIM 4096

typedef float f4  __attribute__((ext_vector_type(4)));
typedef short s8v __attribute__((ext_vector_type(8)));

#if defined(__has_builtin)
#if __has_builtin(__builtin_amdgcn_cvt_pk_bf16_f32)
#define HAVE_CVT_PK 1
#endif
#endif

static __device__ __forceinline__ unsigned int f2bf_pair(float lo, float hi) {
#ifdef HAVE_CVT_PK
    typedef __bf16 bf2 __attribute__((ext_vector_type(2)));
    bf2 p = __builtin_amdgcn_cvt_pk_bf16_f32(lo, hi);
    return __builtin_bit_cast(unsigned int, p);
#else
    unsigned int ul = __builtin_bit_cast(unsigned int, lo);
    unsigned int uh = __builtin_bit_cast(unsigned int, hi);
    ul = ul + 0x7fffu + ((ul >> 16) & 1u);
    uh = uh + 0x7fffu + ((uh >> 16) & 1u);
    return (uh & 0xffff0000u) | (ul >> 16);
#endif
}

static __device__ __forceinline__ s8v cvt8(f4 a, f4 b) {
    unsigned int u4[4] = { f2bf_pair(a[0], a[1]), f2bf_pair(a[2], a[3]),
                           f2bf_pair(b[0], b[1]), f2bf_pair(b[2], b[3]) };
    return __builtin_bit_cast(s8v, u4);
}

#define MFMA(a, b, c) __builtin_amdgcn_mfma_f32_16x16x32_bf16((a), (b), (c), 0, 0, 0)

// GEMM over one n-half: grid (2 n-halves, 256 i-tiles) = 512 blocks ->
// 2 blocks/CU, 4 waves/SIMD (vs R2-fused's 1 block/CU, 2 waves/SIMD).
// 512 threads (kh = w&3 k-tile, nh = w>>2 n-sub-half of the 128-col chunk).
// 16 double-buffered chunk steps (XOR-swizzled LDS, raw lgkm-only barrier,
// global prefetch distance 2, named regs per rule #20). Writes one 4 KB
// fp32 partial per block; part total = 2 MB (vs baseline's 16 MB).
__global__ __launch_bounds__(512) void gemm_kernel(
    const float* __restrict__ zs, const float* __restrict__ X,
    float* __restrict__ part, float* __restrict__ out) {
    __shared__ s8v zsP[2][1024];   // 64 k x 128 n bf16, dbuf (32 KB)
    __shared__ s8v xP [2][256];    // 16 i x 128 n bf16, dbuf (8 KB)
    __shared__ f4  accx[256];      // nh=1 partial accs (4 KB)

    const int tid  = threadIdx.x;
    const int lane = tid & 63;
    const int w    = tid >> 6;
    const int kh   = w & 3;
    const int nh   = w >> 2;
    const int nb   = blockIdx.x * 2048;   // n-half base
    const int i0   = blockIdx.y * 16;

    // out-zeroing folded in: epilogue's atomics are in the NEXT
    // stream-ordered dispatch -- safe (baseline-verified pattern).
    if (blockIdx.x == 0 && blockIdx.y == 0 && tid == 0) *out = 0.f;

    // ---- staging geometry (write side) ----
    const int zr  = tid >> 3;                       // zs row (k), 0..63
    const int zc  = tid & 7;                        // granule col base, +8 for 2nd
    const int zi0 = zr * 16 + (zc ^ (zr & 7));      // XOR swizzle (R8-verified)
    const int zi1 = zi0 + 8;
    const float* gz = zs + (size_t)zr * N_DIM + nb + zc * 8;

    const int xr  = (tid & 255) >> 4;               // X row (i), 0..15 (tid<256)
    const int xc  = tid & 15;
    const int xi  = xr * 16 + (xc ^ (xr & 7));
    const float* gx = X + (size_t)(i0 + xr) * N_DIM + nb + xc * 8;

    // ---- read-side swizzled indices (row&7 == lane&7 for both A and B) ----
    const int arow = kh * 16 + (lane & 15);
    const int brow = lane & 15;
    const int cb0  = nh * 8 + (lane >> 4);          // unswizzled granule col, step 0
    const int ai0  = arow * 16 + ((cb0    ) ^ (lane & 7));
    const int ai1  = arow * 16 + ((cb0 + 4) ^ (lane & 7));
    const int bi0  = brow * 16 + ((cb0    ) ^ (lane & 7));
    const int bi1  = brow * 16 + ((cb0 + 4) ^ (lane & 7));

    // ---- prologue: prefetch chunk 0 into A-regs, chunk 1 into B-regs ----
    f4 rzA0, rzA1, rzA2, rzA3, rzB0, rzB1, rzB2, rzB3;
    f4 rxA0 = {}, rxA1 = {}, rxB0 = {}, rxB1 = {};
    rzA0 = *(const f4*)(gz);       rzA1 = *(const f4*)(gz + 4);
    rzA2 = *(const f4*)(gz + 64);  rzA3 = *(const f4*)(gz + 68);
    rzB0 = *(const f4*)(gz + 128); rzB1 = *(const f4*)(gz + 132);
    rzB2 = *(const f4*)(gz + 192); rzB3 = *(const f4*)(gz + 196);
    if (tid < 256) {
        rxA0 = *(const f4*)(gx);       rxA1 = *(const f4*)(gx + 4);
        rxB0 = *(const f4*)(gx + 128); rxB1 = *(const f4*)(gx + 132);
    }

    f4 acc = {};

#define STEP(L, BI, T)                                                        \
    {                                                                         \
        s8v pz0 = cvt8(rz##L##0, rz##L##1);                                   \
        s8v pz1 = cvt8(rz##L##2, rz##L##3);                                   \
        s8v px0 = {};                                                         \
        if (tid < 256) px0 = cvt8(rx##L##0, rx##L##1);                        \
        if ((T) < 14) {   /* issue chunk T+2 into the slot just consumed */   \
            const float* z = gz + ((T) + 2) * 128;                            \
            rz##L##0 = *(const f4*)(z);      rz##L##1 = *(const f4*)(z + 4);  \
            rz##L##2 = *(const f4*)(z + 64); rz##L##3 = *(const f4*)(z + 68); \
            if (tid < 256) {                                                  \
                const float* x = gx + ((T) + 2) * 128;                        \
                rx##L##0 = *(const f4*)(x);  rx##L##1 = *(const f4*)(x + 4);  \
            }                                                                 \
        }                                                                     \
        zsP[BI][zi0] = pz0; zsP[BI][zi1] = pz1;                               \
        if (tid < 256) xP[BI][xi] = px0;                                      \
        asm volatile("s_waitcnt lgkmcnt(0)\n\ts_barrier" ::: "memory");       \
        s8v a0 = zsP[BI][ai0], b0 = xP[BI][bi0];                              \
        s8v a1 = zsP[BI][ai1], b1 = xP[BI][bi1];                              \
        acc = MFMA(a0, b0, acc);                                              \
        acc = MFMA(a1, b1, acc);                                              \
    }

    for (int m = 0; m < 8; ++m) {
        STEP(A, 0, 2 * m)
        STEP(B, 1, 2 * m + 1)
    }
#undef STEP

    // ---- cross-wave combine (nh=1 -> nh=0), write one f4 granule/thread ----
    if (nh == 1) accx[kh * 64 + lane] = acc;
    __syncthreads();
    if (nh == 0) {
        f4 o = accx[tid];                 // tid == kh*64+lane for nh==0
        f4 s; s[0] = acc[0] + o[0]; s[1] = acc[1] + o[1];
              s[2] = acc[2] + o[2]; s[3] = acc[3] + o[3];
        ((f4*)part)[(blockIdx.y * 2 + blockIdx.x) * 256 + tid] = s;
    }
}

// Epilogue: grid 256 (one 16-row i-tile each), 256 threads. Sums the two
// n-half partials (dense 16 B/lane, L2-hot), exact-fp32 num/den, one
// atomicAdd per block.
__global__ __launch_bounds__(256) void epilogue_kernel(
    const float* __restrict__ part, const float* __restrict__ zs,
    const float* __restrict__ X, const float* __restrict__ varp,
    float* __restrict__ out) {
    const int tid  = threadIdx.x;
    const int lane = tid & 63;
    const int w    = tid >> 6;       // kh
    const int it   = blockIdx.x;
    const f4* pp   = (const f4*)part;

    f4 a = pp[(it * 2 + 0) * 256 + tid];
    f4 b = pp[(it * 2 + 1) * 256 + tid];
    f4 s; s[0] = a[0] + b[0]; s[1] = a[1] + b[1];
          s[2] = a[2] + b[2]; s[3] = a[3] + b[3];

    // C/D layout: col = lane&15 (i), row = (lane>>4)*4 + r (k)
    const int   i   = it * 16 + (lane & 15);
    const int   k0  = w * 16 + (lane >> 4) * 4;
    const float dg  = X[(size_t)i * (N_DIM + 1)];
    const float var = varp[0];

    float vsum = 0.f;
    #pragma unroll
    for (int r = 0; r < 4; ++r) {
        const float num = zs[(size_t)(k0 + r) * N_DIM + i] * dg;   // exact fp32
        const float den = s[r] - num;
        vsum += num / (var + den);
    }
    #pragma unroll
    for (int off = 32; off >= 1; off >>= 1) vsum += __shfl_down(vsum, off);
    __shared__ float wred[4];
    if (lane == 0) wred[w] = vsum;
    __syncthreads();
    if (tid == 0)
        atomicAdd(out, -(wred[0] + wred[1] + wred[2] + wred[3]) * (1.0f / 64.0f));
}

extern "C" void kernel_launch(void* const* d_in, const int* in_sizes, int n_in,
                              void* d_out, int out_size, void* d_ws, size_t ws_size,
                              hipStream_t stream) {
    const float* zs   = (const float*)d_in[0];
    const float* X    = (const float*)d_in[1];
    const float* varp = (const float*)d_in[2];
    float* out  = (float*)d_out;
    float* part = (float*)d_ws;      // 512 blocks x 4 KB = 2 MB

    hipLaunchKernelGGL(gemm_kernel, dim3(2, 256), dim3(512), 0, stream,
                       zs, X, part, out);
    hipLaunchKernelGGL(epilogue_kernel, dim3(256), dim3(256), 0, stream,
                       part, zs, X, varp, out);
}

// Round 4
// 108.725 us; speedup vs baseline: 1.0445x; 1.0324x over previous
//
#include <hip/hip_runtime.h>

#define N_DIM 4096
#define NE    16            // n split 16 ways -> 256 cols/block, 4 chunks of 64

typedef float f4  __attribute__((ext_vector_type(4)));
typedef short s8v __attribute__((ext_vector_type(8)));

#if defined(__has_builtin)
#if __has_builtin(__builtin_amdgcn_cvt_pk_bf16_f32)
#define HAVE_CVT_PK 1
#endif
#endif

static __device__ __forceinline__ unsigned int f2bf_pair(float lo, float hi) {
#ifdef HAVE_CVT_PK
    typedef __bf16 bf2 __attribute__((ext_vector_type(2)));
    bf2 p = __builtin_amdgcn_cvt_pk_bf16_f32(lo, hi);
    return __builtin_bit_cast(unsigned int, p);
#else
    unsigned int ul = __builtin_bit_cast(unsigned int, lo);
    unsigned int uh = __builtin_bit_cast(unsigned int, hi);
    ul = ul + 0x7fffu + ((ul >> 16) & 1u);
    uh = uh + 0x7fffu + ((uh >> 16) & 1u);
    return (uh & 0xffff0000u) | (ul >> 16);
#endif
}

static __device__ __forceinline__ s8v cvt8(f4 a, f4 b) {
    unsigned int u4[4] = { f2bf_pair(a[0], a[1]), f2bf_pair(a[2], a[3]),
                           f2bf_pair(b[0], b[1]), f2bf_pair(b[2], b[3]) };
    return __builtin_bit_cast(s8v, u4);
}

#define MFMA(a, b, c) __builtin_amdgcn_mfma_f32_16x16x32_bf16((a), (b), (c), 0, 0, 0)

// R9 gemm (XOR-swizzled conflict-free LDS, raw lgkm-only barrier, prefetch
// distance 2, no fences) + out-zeroing folded in (block (0,0) writes out=0;
// the epilogue's atomics are in the NEXT stream-ordered dispatch — safe).
// Reverted to this exact structure after R2 (full fusion, 1 block/CU) and
// R3 (2-way n-split, 2 MFMA/barrier) both lost ~5-6 µs: at the HBM floor,
// 4 blocks/CU + 8 MFMA/barrier is what hides the per-chunk barrier drain,
// and the 16 MB part round-trip is L3-absorbed (~1 µs of fill writeback).
__global__ __launch_bounds__(256) void gemm_part_kernel(
    const float* __restrict__ zs, const float* __restrict__ X,
    float* __restrict__ part, float* __restrict__ out) {
    __shared__ s8v zsP[2][512];   // 64 k x 64 n bf16, dbuf (16 KB)
    __shared__ s8v xP [2][512];   // 64 i x 64 n bf16, dbuf (16 KB)

    const int tid  = threadIdx.x;
    const int lane = tid & 63;
    const int w    = tid >> 6;
    const int n0   = blockIdx.x * 256;
    const int i0   = blockIdx.y * 64;

    if (blockIdx.x == 0 && blockIdx.y == 0 && tid == 0) *out = 0.f;

    const int r0  = tid >> 3;
    const int c8w = tid & 7;
    const int g0  = r0 * 8 + (c8w ^ (r0 & 7));   // XOR swizzle (R8-verified)
    const int g1  = g0 + 256;

    const float* gz0 = zs + (size_t)r0 * N_DIM + n0 + c8w * 8;
    const float* gz1 = gz0 + (size_t)32 * N_DIM;
    const float* gx0 = X  + (size_t)(i0 + r0) * N_DIM + n0 + c8w * 8;
    const float* gx1 = gx0 + (size_t)32 * N_DIM;

    f4 rz[2][4], rx[2][4];
    #pragma unroll
    for (int p = 0; p < 2; ++p) {
        const int off = p * 64;
        rz[p][0] = *(const f4*)(gz0 + off); rz[p][1] = *(const f4*)(gz0 + off + 4);
        rz[p][2] = *(const f4*)(gz1 + off); rz[p][3] = *(const f4*)(gz1 + off + 4);
        rx[p][0] = *(const f4*)(gx0 + off); rx[p][1] = *(const f4*)(gx0 + off + 4);
        rx[p][2] = *(const f4*)(gx1 + off); rx[p][3] = *(const f4*)(gx1 + off + 4);
    }

    f4 acc[2][2] = {};
    const int kh  = (w & 1) * 2;
    const int ih  = (w >> 1) * 2;
    const int u0  = (lane & 15) * 8;
    const int xs0 = (lane >> 4) ^ (lane & 7);
    const int xs1 = xs0 ^ 4;

    #pragma unroll
    for (int c = 0; c < 4; ++c) {
        const int buf = c & 1;
        s8v pz0 = cvt8(rz[buf][0], rz[buf][1]);
        s8v pz1 = cvt8(rz[buf][2], rz[buf][3]);
        s8v px0 = cvt8(rx[buf][0], rx[buf][1]);
        s8v px1 = cvt8(rx[buf][2], rx[buf][3]);
        if (c < 2) {   // issue chunk c+2 into the slot just consumed
            const int off = (c + 2) * 64;
            rz[buf][0] = *(const f4*)(gz0 + off); rz[buf][1] = *(const f4*)(gz0 + off + 4);
            rz[buf][2] = *(const f4*)(gz1 + off); rz[buf][3] = *(const f4*)(gz1 + off + 4);
            rx[buf][0] = *(const f4*)(gx0 + off); rx[buf][1] = *(const f4*)(gx0 + off + 4);
            rx[buf][2] = *(const f4*)(gx1 + off); rx[buf][3] = *(const f4*)(gx1 + off + 4);
        }
        zsP[buf][g0] = pz0;  zsP[buf][g1] = pz1;
        xP[buf][g0]  = px0;  xP[buf][g1]  = px1;
        asm volatile("s_waitcnt lgkmcnt(0)\n\ts_barrier" ::: "memory");

        s8v a0s0 = zsP[buf][(kh    ) * 128 + u0 + xs0];
        s8v a0s1 = zsP[buf][(kh    ) * 128 + u0 + xs1];
        s8v a1s0 = zsP[buf][(kh + 1) * 128 + u0 + xs0];
        s8v a1s1 = zsP[buf][(kh + 1) * 128 + u0 + xs1];
        s8v b0s0 = xP [buf][(ih    ) * 128 + u0 + xs0];
        s8v b0s1 = xP [buf][(ih    ) * 128 + u0 + xs1];
        s8v b1s0 = xP [buf][(ih + 1) * 128 + u0 + xs0];
        s8v b1s1 = xP [buf][(ih + 1) * 128 + u0 + xs1];

        acc[0][0] = MFMA(a0s0, b0s0, acc[0][0]);
        acc[0][1] = MFMA(a0s0, b1s0, acc[0][1]);
        acc[1][0] = MFMA(a1s0, b0s0, acc[1][0]);
        acc[1][1] = MFMA(a1s0, b1s0, acc[1][1]);
        acc[0][0] = MFMA(a0s1, b0s1, acc[0][0]);
        acc[0][1] = MFMA(a0s1, b1s1, acc[0][1]);
        acc[1][0] = MFMA(a1s1, b0s1, acc[1][0]);
        acc[1][1] = MFMA(a1s1, b1s1, acc[1][1]);
    }

    // partial store: [it][ne][j], j = (ktile*4 + itile)*64 + lane — consumer-dense
    f4* pp = (f4*)part;
    const int tb = (blockIdx.y * NE + blockIdx.x) * 1024;
    #pragma unroll
    for (int a = 0; a < 2; ++a)
        #pragma unroll
        for (int b = 0; b < 2; ++b)
            pp[tb + ((kh + a) * 4 + (ih + b)) * 64 + lane] = acc[a][b];
}

// Epilogue: grid (4 k-quarters, 64 i-tiles); one f4 granule per thread summed
// over the 16 ne partials (dense 16 B/lane), exact-fp32 num/den, one atomic
// per block. Change vs R0: ne-loop fully unrolled (4 -> 16 loads in flight;
// the loop is a latency-bound L3 read).
__global__ __launch_bounds__(256) void epilogue_kernel(
    const float* __restrict__ part, const float* __restrict__ zs,
    const float* __restrict__ X, const float* __restrict__ varp,
    float* __restrict__ out) {
    const int tid  = threadIdx.x;
    const int lane = tid & 63;
    const int w    = tid >> 6;
    const int q    = blockIdx.x;     // k-quarter == ktile (j>>8)
    const int it   = blockIdx.y;
    const f4* pp   = (const f4*)part;

    const int jj = q * 256 + tid;
    f4 v[NE];
    #pragma unroll
    for (int ne = 0; ne < NE; ++ne)
        v[ne] = pp[(it * NE + ne) * 1024 + jj];
    f4 s = {};
    #pragma unroll
    for (int ne = 0; ne < NE; ++ne) {
        s[0] += v[ne][0]; s[1] += v[ne][1]; s[2] += v[ne][2]; s[3] += v[ne][3];
    }
    // decode: itl = w; C/D: col = lane&15 (i), row = (lane>>4)*4 + r (k)
    const int   i   = it * 64 + w * 16 + (lane & 15);
    const int   k0  = q * 16 + (lane >> 4) * 4;
    const float dg  = X[(size_t)i * (N_DIM + 1)];
    const float var = varp[0];

    float vsum = 0.f;
    #pragma unroll
    for (int r = 0; r < 4; ++r) {
        float num = zs[(size_t)(k0 + r) * N_DIM + i] * dg;   // exact fp32
        float den = s[r] - num;
        vsum += num / (var + den);
    }
    #pragma unroll
    for (int off = 32; off >= 1; off >>= 1) vsum += __shfl_down(vsum, off);
    __shared__ float wsum[4];
    if (lane == 0) wsum[w] = vsum;
    __syncthreads();
    if (tid == 0)
        atomicAdd(out, -(wsum[0] + wsum[1] + wsum[2] + wsum[3]) * (1.0f / 64.0f));
}

extern "C" void kernel_launch(void* const* d_in, const int* in_sizes, int n_in,
                              void* d_out, int out_size, void* d_ws, size_t ws_size,
                              hipStream_t stream) {
    const float* zs   = (const float*)d_in[0];
    const float* X    = (const float*)d_in[1];
    const float* varp = (const float*)d_in[2];
    float* out  = (float*)d_out;
    float* part = (float*)d_ws;     // 64 it x 16 ne x 16 KB = 16 MB

    hipLaunchKernelGGL(gemm_part_kernel, dim3(NE, 64), dim3(256), 0, stream,
                       zs, X, part, out);
    hipLaunchKernelGGL(epilogue_kernel, dim3(4, 64), dim3(256), 0, stream,
                       part, zs, X, varp, out);
}